// Round 2
// baseline (467.712 us; speedup 1.0000x reference)
//
#include <hip/hip_runtime.h>
#include <hip/hip_bf16.h>

// dims
#define NB2 128
#define LQK 256
#define DIM 256
#define NH 8
#define CC 32

typedef __bf16 bf16x8 __attribute__((ext_vector_type(8)));
typedef float f32x4 __attribute__((ext_vector_type(4)));

#define MFMA16 __builtin_amdgcn_mfma_f32_16x16x32_bf16

// load 8 contiguous floats, round-to-nearest-even to bf16 fragment
static __device__ __forceinline__ bf16x8 ld8(const float* __restrict__ p) {
    f32x4 a = *(const f32x4*)p;
    f32x4 b = *(const f32x4*)(p + 4);
    bf16x8 r;
    r[0] = (__bf16)a[0]; r[1] = (__bf16)a[1]; r[2] = (__bf16)a[2]; r[3] = (__bf16)a[3];
    r[4] = (__bf16)b[0]; r[5] = (__bf16)b[1]; r[6] = (__bf16)b[2]; r[7] = (__bf16)b[3];
    return r;
}

// ---------------- Kernel 1: fused QKVG projection -------------------------
// N dim = 1024 = [q(256) | k(256) | v(256) | g(256)]
// grid (512, 16), block 256 (4 waves), 64x64 tile per block.
__global__ __launch_bounds__(256) void k_proj(
    const float* __restrict__ qd, const float* __restrict__ kvd,
    const float* __restrict__ Wq, const float* __restrict__ Wk,
    const float* __restrict__ Wv, const float* __restrict__ Wg,
    const float* __restrict__ bg,
    __bf16* __restrict__ wsq, __bf16* __restrict__ wsk,
    __bf16* __restrict__ wsvT, __bf16* __restrict__ wsg)
{
    const int bm = blockIdx.x;          // 0..511  (M = 32768)
    const int bn = blockIdx.y;          // 0..15   (N = 1024)
    const int t = bn >> 2;              // 0=q 1=k 2=v 3=g
    const float* X = (t == 0 || t == 3) ? qd : kvd;
    const float* W = (t == 0) ? Wq : (t == 1) ? Wk : (t == 2) ? Wv : Wg;

    const int lane = threadIdx.x & 63;
    const int w = threadIdx.x >> 6;
    const int g = lane >> 4, kg = g * 8, c0 = lane & 15;
    const int m0 = bm * 64 + w * 16;

    f32x4 acc[4] = {};
    const float* arow = X + (size_t)(m0 + c0) * DIM;
    for (int k0 = 0; k0 < DIM; k0 += 32) {
        bf16x8 a = ld8(arow + k0 + kg);
#pragma unroll
        for (int nt = 0; nt < 4; nt++) {
            int col = bn * 64 + nt * 16 + c0;
            bf16x8 b = ld8(W + (size_t)(col & 255) * DIM + k0 + kg);
            acc[nt] = MFMA16(a, b, acc[nt], 0, 0, 0);
        }
    }
    // epilogue: D layout col=lane&15, row=4*(lane>>4)+reg
#pragma unroll
    for (int nt = 0; nt < 4; nt++) {
        int n = bn * 64 + nt * 16 + c0;
        int r = n & 255, h = r >> 5, c = r & 31;
#pragma unroll
        for (int reg = 0; reg < 4; reg++) {
            int m = m0 + g * 4 + reg;
            int b2 = m >> 8, l = m & 255;
            float v = acc[nt][reg];
            if (t == 0) {
                v *= 0.17677669529663689f;   // C^-0.5
                wsq[((size_t)(b2 * NH + h) * LQK + l) * CC + c] = (__bf16)v;
            } else if (t == 1) {
                wsk[((size_t)(b2 * NH + h) * LQK + l) * CC + c] = (__bf16)v;
            } else if (t == 2) {
                wsvT[((size_t)(b2 * NH + h) * CC + c) * LQK + l] = (__bf16)v;
            } else {
                v += bg[r];
                v = 1.0f / (1.0f + __expf(-v));
                wsg[((size_t)(b2 * NH + h) * LQK + l) * CC + c] = (__bf16)v;
            }
        }
    }
}

// ---------------- Kernel 2: attention core --------------------------------
// grid 4096 = b2(128) * h(8) * qtile(4); block 256 (4 waves), wave = 16 q-rows
__global__ __launch_bounds__(256) void k_attn(
    const __bf16* __restrict__ wsq, const __bf16* __restrict__ wsk,
    const __bf16* __restrict__ wsvT, const __bf16* __restrict__ wsg,
    const float* __restrict__ bias, const float* __restrict__ nbb,
    __bf16* __restrict__ wswa)
{
    __shared__ __bf16 P[4][16][264];   // wave-private P strips, padded stride

    const int bid = blockIdx.x;
    const int b2 = bid >> 5, h = (bid >> 2) & 7, qt = bid & 3;
    const int lane = threadIdx.x & 63, w = threadIdx.x >> 6;
    const int g = lane >> 4, kg = g * 8, c0 = lane & 15;
    const int qbase = qt * 64 + w * 16;

    const __bf16* qp = wsq + (size_t)(b2 * NH + h) * LQK * CC;
    const __bf16* kp = wsk + (size_t)(b2 * NH + h) * LQK * CC;
    const __bf16* vT = wsvT + (size_t)(b2 * NH + h) * CC * LQK;
    const __bf16* gp = wsg + (size_t)(b2 * NH + h) * LQK * CC;
    const float* bp = bias + (size_t)(b2 * NH + h) * LQK * LQK;
    const float* np = nbb + (size_t)h * LQK * LQK;

    // S = q @ k^T  (K=32 -> single MFMA per 16x16 tile)
    f32x4 s[16];
    bf16x8 a = *(const bf16x8*)(qp + (size_t)(qbase + c0) * CC + kg);
#pragma unroll
    for (int nt = 0; nt < 16; nt++) {
        bf16x8 b = *(const bf16x8*)(kp + (size_t)(nt * 16 + c0) * CC + kg);
        f32x4 z = {};
        s[nt] = MFMA16(a, b, z, 0, 0, 0);
    }
    // + bias + nonbatched_bias (both fp32, exact)
#pragma unroll
    for (int nt = 0; nt < 16; nt++) {
#pragma unroll
        for (int reg = 0; reg < 4; reg++) {
            int row = qbase + g * 4 + reg;
            int col = nt * 16 + c0;
            s[nt][reg] += bp[(size_t)row * LQK + col] + np[(size_t)row * LQK + col];
        }
    }
    // softmax over 256 cols; row r=4g+reg lives in contiguous 16-lane group
    float mx[4], sm[4];
#pragma unroll
    for (int reg = 0; reg < 4; reg++) {
        float m_ = s[0][reg];
#pragma unroll
        for (int nt = 1; nt < 16; nt++) m_ = fmaxf(m_, s[nt][reg]);
#pragma unroll
        for (int d = 1; d < 16; d <<= 1) m_ = fmaxf(m_, __shfl_xor(m_, d, 64));
        mx[reg] = m_;
        sm[reg] = 0.0f;
    }
#pragma unroll
    for (int nt = 0; nt < 16; nt++) {
#pragma unroll
        for (int reg = 0; reg < 4; reg++) {
            float e = __expf(s[nt][reg] - mx[reg]);
            s[nt][reg] = e;
            sm[reg] += e;
        }
    }
#pragma unroll
    for (int reg = 0; reg < 4; reg++) {
        float t_ = sm[reg];
#pragma unroll
        for (int d = 1; d < 16; d <<= 1) t_ += __shfl_xor(t_, d, 64);
        sm[reg] = 1.0f / t_;
    }
    // P (unnormalized) -> LDS, row-major [16][264]
#pragma unroll
    for (int nt = 0; nt < 16; nt++)
#pragma unroll
        for (int reg = 0; reg < 4; reg++)
            P[w][g * 4 + reg][nt * 16 + c0] = (__bf16)s[nt][reg];
    __syncthreads();

    // O = P @ V   (vT is [c][l] so B-fragments are contiguous)
    f32x4 o[2] = {};
#pragma unroll
    for (int kt = 0; kt < 8; kt++) {
        bf16x8 pa = *(const bf16x8*)(&P[w][c0][kt * 32 + kg]);
#pragma unroll
        for (int nt = 0; nt < 2; nt++) {
            bf16x8 vb = *(const bf16x8*)(vT + (size_t)(nt * 16 + c0) * LQK + kt * 32 + kg);
            o[nt] = MFMA16(pa, vb, o[nt], 0, 0, 0);
        }
    }
    // 1/sum, gate, store wa[b2][l][h*32+c]
#pragma unroll
    for (int nt = 0; nt < 2; nt++) {
#pragma unroll
        for (int reg = 0; reg < 4; reg++) {
            int row = qbase + g * 4 + reg;
            int c = nt * 16 + c0;
            float val = o[nt][reg] * sm[reg];
            val *= (float)gp[(size_t)row * CC + c];
            wswa[((size_t)(b2 * LQK + row)) * (NH * CC) + h * CC + c] = (__bf16)val;
        }
    }
}

// ---------------- Kernel 3: output projection -----------------------------
// out = wa @ Wo^T + bo ; M=32768, N=256, K=256. grid (512,4), block 256.
__global__ __launch_bounds__(256) void k_out(
    const __bf16* __restrict__ wa, const float* __restrict__ Wo,
    const float* __restrict__ bo, float* __restrict__ out)
{
    const int bm = blockIdx.x, bn = blockIdx.y;
    const int lane = threadIdx.x & 63, w = threadIdx.x >> 6;
    const int g = lane >> 4, kg = g * 8, c0 = lane & 15;
    const int m0 = bm * 64 + w * 16;

    f32x4 acc[4] = {};
    const __bf16* arow = wa + (size_t)(m0 + c0) * 256;
    for (int k0 = 0; k0 < 256; k0 += 32) {
        bf16x8 a = *(const bf16x8*)(arow + k0 + kg);
#pragma unroll
        for (int nt = 0; nt < 4; nt++) {
            int col = bn * 64 + nt * 16 + c0;
            bf16x8 b = ld8(Wo + (size_t)col * 256 + k0 + kg);
            acc[nt] = MFMA16(a, b, acc[nt], 0, 0, 0);
        }
    }
#pragma unroll
    for (int nt = 0; nt < 4; nt++) {
        int n = bn * 64 + nt * 16 + c0;
        float bo_ = bo[n];
#pragma unroll
        for (int reg = 0; reg < 4; reg++) {
            int m = m0 + g * 4 + reg;
            out[(size_t)m * 256 + n] = acc[nt][reg] + bo_;
        }
    }
}

// ---------------- launcher ------------------------------------------------
extern "C" void kernel_launch(void* const* d_in, const int* in_sizes, int n_in,
                              void* d_out, int out_size, void* d_ws, size_t ws_size,
                              hipStream_t stream) {
    const float* qd  = (const float*)d_in[0];
    const float* kvd = (const float*)d_in[1];
    const float* bias = (const float*)d_in[2];
    const float* nbb = (const float*)d_in[3];
    const float* Wq = (const float*)d_in[4];
    const float* Wk = (const float*)d_in[5];
    const float* Wv = (const float*)d_in[6];
    const float* Wg = (const float*)d_in[7];
    const float* bg = (const float*)d_in[8];
    const float* Wo = (const float*)d_in[9];
    const float* bo = (const float*)d_in[10];
    float* out = (float*)d_out;

    const size_t NTOK = (size_t)NB2 * LQK * NH * CC;  // 8,388,608
    __bf16* ws = (__bf16*)d_ws;
    __bf16* wsq  = ws;
    __bf16* wsk  = wsq + NTOK;
    __bf16* wsvT = wsk + NTOK;
    __bf16* wsg  = wsvT + NTOK;
    __bf16* wswa = wsg + NTOK;

    k_proj<<<dim3(512, 16), 256, 0, stream>>>(qd, kvd, Wq, Wk, Wv, Wg, bg,
                                              wsq, wsk, wsvT, wsg);
    k_attn<<<dim3(4096), 256, 0, stream>>>(wsq, wsk, wsvT, wsg, bias, nbb, wswa);
    k_out<<<dim3(512, 4), 256, 0, stream>>>(wswa, Wo, bo, out);
}

// Round 3
// 346.130 us; speedup vs baseline: 1.3513x; 1.3513x over previous
//
#include <hip/hip_runtime.h>
#include <hip/hip_bf16.h>

// dims
#define NB2 128
#define LQK 256
#define DIM 256
#define NH 8
#define CC 32

typedef __bf16 bf16x8 __attribute__((ext_vector_type(8)));
typedef float f32x4 __attribute__((ext_vector_type(4)));

#define MFMA16 __builtin_amdgcn_mfma_f32_16x16x32_bf16

// load 8 contiguous floats, RNE to bf16 fragment
static __device__ __forceinline__ bf16x8 ld8(const float* __restrict__ p) {
    f32x4 a = *(const f32x4*)p;
    f32x4 b = *(const f32x4*)(p + 4);
    bf16x8 r;
    r[0] = (__bf16)a[0]; r[1] = (__bf16)a[1]; r[2] = (__bf16)a[2]; r[3] = (__bf16)a[3];
    r[4] = (__bf16)b[0]; r[5] = (__bf16)b[1]; r[6] = (__bf16)b[2]; r[7] = (__bf16)b[3];
    return r;
}

// ---------------- Kernel 0: convert weights fp32 -> bf16 ------------------
// 5 matrices of 65536 elements each: Wq, Wk, Wv, Wg, Wo  (laid out
// consecutively in ws). 320 blocks x 256 threads x 4 elems.
__global__ __launch_bounds__(256) void k_wcvt(
    const float* __restrict__ Wq, const float* __restrict__ Wk,
    const float* __restrict__ Wv, const float* __restrict__ Wg,
    const float* __restrict__ Wo, __bf16* __restrict__ dst)
{
    int i = (blockIdx.x * 256 + threadIdx.x) * 4;     // 0 .. 327679*? (*4)
    int mat = i >> 16;                                 // 0..4
    int off = i & 65535;
    const float* src = (mat == 0) ? Wq : (mat == 1) ? Wk : (mat == 2) ? Wv
                      : (mat == 3) ? Wg : Wo;
    f32x4 v = *(const f32x4*)(src + off);
    __bf16* d = dst + ((size_t)mat << 16) + off;
    d[0] = (__bf16)v[0]; d[1] = (__bf16)v[1]; d[2] = (__bf16)v[2]; d[3] = (__bf16)v[3];
}

// ---------------- Kernel 1: QKVG projection -------------------------------
// grid (512, 4): y = 0:q 1:g 2:k 3:v.  block 256 = 4 waves.
// wave = 16 rows x 256 cols (16 n-tiles), K=256 in 8 steps of 32.
__global__ __launch_bounds__(256) void k_proj(
    const float* __restrict__ qd, const float* __restrict__ kvd,
    const __bf16* __restrict__ wBF,   // [Wq|Wk|Wv|Wg|Wo] bf16
    const float* __restrict__ bg,
    __bf16* __restrict__ wsq, __bf16* __restrict__ wsk,
    __bf16* __restrict__ wsvT, __bf16* __restrict__ wsg)
{
    const int bm = blockIdx.x;          // 0..511  (M = 32768)
    const int t = blockIdx.y;           // 0=q 1=g 2=k 3=v
    const float* X = (t < 2) ? qd : kvd;
    const __bf16* W = wBF + ((size_t)((t == 0) ? 0 : (t == 1) ? 3 : (t == 2) ? 1 : 2) << 16);

    const int lane = threadIdx.x & 63;
    const int w = threadIdx.x >> 6;
    const int g = lane >> 4, kg = g * 8, c0 = lane & 15;
    const int m0 = bm * 64 + w * 16;

    f32x4 acc[16] = {};
    const float* arow = X + (size_t)(m0 + c0) * DIM;
#pragma unroll
    for (int k0 = 0; k0 < DIM; k0 += 32) {
        bf16x8 a = ld8(arow + k0 + kg);
#pragma unroll
        for (int nt = 0; nt < 16; nt++) {
            bf16x8 b = *(const bf16x8*)(W + (size_t)(nt * 16 + c0) * DIM + k0 + kg);
            acc[nt] = MFMA16(a, b, acc[nt], 0, 0, 0);
        }
    }
    // epilogue: D layout col=lane&15, row=4*(lane>>4)+reg
    const int b2 = m0 >> 8;             // 64-row strip never crosses b2
#pragma unroll
    for (int nt = 0; nt < 16; nt++) {
        int n = nt * 16 + c0;           // 0..255
        int h = n >> 5, c = n & 31;
        float bg_ = (t == 1) ? bg[n] : 0.0f;
#pragma unroll
        for (int reg = 0; reg < 4; reg++) {
            int m = m0 + g * 4 + reg;
            int l = m & 255;
            float v = acc[nt][reg];
            size_t base = ((size_t)(b2 * NH + h) * LQK + l) * CC + c;
            if (t == 0) {
                wsq[base] = (__bf16)(v * 0.17677669529663689f);   // C^-0.5
            } else if (t == 1) {
                v += bg_;
                wsg[base] = (__bf16)(1.0f / (1.0f + __expf(-v)));
            } else if (t == 2) {
                wsk[base] = (__bf16)v;
            } else {
                wsvT[((size_t)(b2 * NH + h) * CC + c) * LQK + l] = (__bf16)v;
            }
        }
    }
}

// ---------------- Kernel 2: attention core --------------------------------
// grid 4096 = b2(128) * h(8) * qtile(4); block 256 (4 waves), wave = 16 q-rows
__global__ __launch_bounds__(256) void k_attn(
    const __bf16* __restrict__ wsq, const __bf16* __restrict__ wsk,
    const __bf16* __restrict__ wsvT, const __bf16* __restrict__ wsg,
    const float* __restrict__ bias, const float* __restrict__ nbb,
    __bf16* __restrict__ wswa)
{
    __shared__ __bf16 P[4][16][264];   // wave-private P strips, padded stride

    const int bid = blockIdx.x;
    const int b2 = bid >> 5, h = (bid >> 2) & 7, qt = bid & 3;
    const int lane = threadIdx.x & 63, w = threadIdx.x >> 6;
    const int g = lane >> 4, kg = g * 8, c0 = lane & 15;
    const int qbase = qt * 64 + w * 16;

    const __bf16* qp = wsq + (size_t)(b2 * NH + h) * LQK * CC;
    const __bf16* kp = wsk + (size_t)(b2 * NH + h) * LQK * CC;
    const __bf16* vT = wsvT + (size_t)(b2 * NH + h) * CC * LQK;
    const __bf16* gp = wsg + (size_t)(b2 * NH + h) * LQK * CC;
    const float* bp = bias + (size_t)(b2 * NH + h) * LQK * LQK;
    const float* np = nbb + (size_t)h * LQK * LQK;

    // S = q @ k^T  (K=32 -> single MFMA per 16x16 tile)
    f32x4 s[16];
    bf16x8 a = *(const bf16x8*)(qp + (size_t)(qbase + c0) * CC + kg);
#pragma unroll
    for (int nt = 0; nt < 16; nt++) {
        bf16x8 b = *(const bf16x8*)(kp + (size_t)(nt * 16 + c0) * CC + kg);
        f32x4 z = {};
        s[nt] = MFMA16(a, b, z, 0, 0, 0);
    }
    // + bias + nonbatched_bias (both fp32, exact)
#pragma unroll
    for (int nt = 0; nt < 16; nt++) {
#pragma unroll
        for (int reg = 0; reg < 4; reg++) {
            int row = qbase + g * 4 + reg;
            int col = nt * 16 + c0;
            s[nt][reg] += bp[(size_t)row * LQK + col] + np[(size_t)row * LQK + col];
        }
    }
    // softmax over 256 cols; row r=4g+reg lives in contiguous 16-lane group
    float mx[4], sm[4];
#pragma unroll
    for (int reg = 0; reg < 4; reg++) {
        float m_ = s[0][reg];
#pragma unroll
        for (int nt = 1; nt < 16; nt++) m_ = fmaxf(m_, s[nt][reg]);
#pragma unroll
        for (int d = 1; d < 16; d <<= 1) m_ = fmaxf(m_, __shfl_xor(m_, d, 64));
        mx[reg] = m_;
        sm[reg] = 0.0f;
    }
#pragma unroll
    for (int nt = 0; nt < 16; nt++) {
#pragma unroll
        for (int reg = 0; reg < 4; reg++) {
            float e = __expf(s[nt][reg] - mx[reg]);
            s[nt][reg] = e;
            sm[reg] += e;
        }
    }
#pragma unroll
    for (int reg = 0; reg < 4; reg++) {
        float t_ = sm[reg];
#pragma unroll
        for (int d = 1; d < 16; d <<= 1) t_ += __shfl_xor(t_, d, 64);
        sm[reg] = 1.0f / t_;
    }
    // P (unnormalized) -> LDS, row-major [16][264]
#pragma unroll
    for (int nt = 0; nt < 16; nt++)
#pragma unroll
        for (int reg = 0; reg < 4; reg++)
            P[w][g * 4 + reg][nt * 16 + c0] = (__bf16)s[nt][reg];
    __syncthreads();

    // O = P @ V   (vT is [c][l] so B-fragments are contiguous)
    f32x4 o[2] = {};
#pragma unroll
    for (int kt = 0; kt < 8; kt++) {
        bf16x8 pa = *(const bf16x8*)(&P[w][c0][kt * 32 + kg]);
#pragma unroll
        for (int nt = 0; nt < 2; nt++) {
            bf16x8 vb = *(const bf16x8*)(vT + (size_t)(nt * 16 + c0) * LQK + kt * 32 + kg);
            o[nt] = MFMA16(pa, vb, o[nt], 0, 0, 0);
        }
    }
    // 1/sum, gate, store wa[b2][l][h*32+c]
#pragma unroll
    for (int nt = 0; nt < 2; nt++) {
#pragma unroll
        for (int reg = 0; reg < 4; reg++) {
            int row = qbase + g * 4 + reg;
            int c = nt * 16 + c0;
            float val = o[nt][reg] * sm[reg];
            val *= (float)gp[(size_t)row * CC + c];
            wswa[((size_t)(b2 * LQK + row)) * (NH * CC) + h * CC + c] = (__bf16)val;
        }
    }
}

// ---------------- Kernel 3: output projection -----------------------------
// out = wa @ Wo^T + bo ; M=32768, N=256, K=256. grid (512), block 256.
// wave = 16 rows x 256 cols (16 n-tiles).
__global__ __launch_bounds__(256) void k_out(
    const __bf16* __restrict__ wa, const __bf16* __restrict__ wBF,
    const float* __restrict__ bo, float* __restrict__ out)
{
    const __bf16* Wo = wBF + ((size_t)4 << 16);
    const int bm = blockIdx.x;
    const int lane = threadIdx.x & 63, w = threadIdx.x >> 6;
    const int g = lane >> 4, kg = g * 8, c0 = lane & 15;
    const int m0 = bm * 64 + w * 16;

    f32x4 acc[16] = {};
    const __bf16* arow = wa + (size_t)(m0 + c0) * 256;
#pragma unroll
    for (int k0 = 0; k0 < 256; k0 += 32) {
        bf16x8 a = *(const bf16x8*)(arow + k0 + kg);
#pragma unroll
        for (int nt = 0; nt < 16; nt++) {
            bf16x8 b = *(const bf16x8*)(Wo + (size_t)(nt * 16 + c0) * 256 + k0 + kg);
            acc[nt] = MFMA16(a, b, acc[nt], 0, 0, 0);
        }
    }
#pragma unroll
    for (int nt = 0; nt < 16; nt++) {
        int n = nt * 16 + c0;
        float bo_ = bo[n];
#pragma unroll
        for (int reg = 0; reg < 4; reg++) {
            int m = m0 + g * 4 + reg;
            out[(size_t)m * 256 + n] = acc[nt][reg] + bo_;
        }
    }
}

// ---------------- launcher ------------------------------------------------
extern "C" void kernel_launch(void* const* d_in, const int* in_sizes, int n_in,
                              void* d_out, int out_size, void* d_ws, size_t ws_size,
                              hipStream_t stream) {
    const float* qd  = (const float*)d_in[0];
    const float* kvd = (const float*)d_in[1];
    const float* bias = (const float*)d_in[2];
    const float* nbb = (const float*)d_in[3];
    const float* Wq = (const float*)d_in[4];
    const float* Wk = (const float*)d_in[5];
    const float* Wv = (const float*)d_in[6];
    const float* Wg = (const float*)d_in[7];
    const float* bg = (const float*)d_in[8];
    const float* Wo = (const float*)d_in[9];
    const float* bo = (const float*)d_in[10];
    float* out = (float*)d_out;

    const size_t NTOK = (size_t)NB2 * LQK * NH * CC;  // 8,388,608
    __bf16* ws = (__bf16*)d_ws;
    __bf16* wsq  = ws;
    __bf16* wsk  = wsq + NTOK;
    __bf16* wsvT = wsk + NTOK;
    __bf16* wsg  = wsvT + NTOK;
    __bf16* wswa = wsg + NTOK;
    __bf16* wBF  = wswa + NTOK;        // 5 * 65536 bf16 weights

    k_wcvt<<<dim3(320), 256, 0, stream>>>(Wq, Wk, Wv, Wg, Wo, wBF);
    k_proj<<<dim3(512, 4), 256, 0, stream>>>(qd, kvd, wBF, bg,
                                             wsq, wsk, wsvT, wsg);
    k_attn<<<dim3(4096), 256, 0, stream>>>(wsq, wsk, wsvT, wsg, bias, nbb, wswa);
    k_out<<<dim3(512), 256, 0, stream>>>(wswa, wBF, bo, out);
}

// Round 4
// 253.598 us; speedup vs baseline: 1.8443x; 1.3649x over previous
//
#include <hip/hip_runtime.h>
#include <hip/hip_bf16.h>

// dims
#define NB2 128
#define LQK 256
#define DIM 256
#define NH 8
#define CC 32

typedef __bf16 bf16x8 __attribute__((ext_vector_type(8)));
typedef __bf16 bf16x4 __attribute__((ext_vector_type(4)));
typedef float f32x4 __attribute__((ext_vector_type(4)));

#define MFMA16 __builtin_amdgcn_mfma_f32_16x16x32_bf16

// LDS tile: 128 rows x 64 k, padded row stride 72 bf16 (144 B) -> 2-way max
#define TP 72

// ---------------- Kernel 0: convert weights fp32 -> bf16 ------------------
__global__ __launch_bounds__(256) void k_wcvt(
    const float* __restrict__ Wq, const float* __restrict__ Wk,
    const float* __restrict__ Wv, const float* __restrict__ Wg,
    const float* __restrict__ Wo, __bf16* __restrict__ dst)
{
    int i = (blockIdx.x * 256 + threadIdx.x) * 4;
    int mat = i >> 16;
    int off = i & 65535;
    const float* src = (mat == 0) ? Wq : (mat == 1) ? Wk : (mat == 2) ? Wv
                      : (mat == 3) ? Wg : Wo;
    f32x4 v = *(const f32x4*)(src + off);
    __bf16* d = dst + ((size_t)mat << 16) + off;
    d[0] = (__bf16)v[0]; d[1] = (__bf16)v[1]; d[2] = (__bf16)v[2]; d[3] = (__bf16)v[3];
}

// ---------------- Kernel 1: QKVG projection (tiled GEMM) ------------------
// M=32768, N=1024=[q|k|v|g], K=256.  grid (256 mb, 8 nb), 256 thr (4 waves).
// Block tile 128x128, BK=64 double-buffered, wave = 64x64 quadrant.
__global__ __launch_bounds__(256, 2) void k_proj(
    const float* __restrict__ qd, const float* __restrict__ kvd,
    const __bf16* __restrict__ wBF, const float* __restrict__ bg,
    __bf16* __restrict__ wsq, __bf16* __restrict__ wsk,
    __bf16* __restrict__ wsvT, __bf16* __restrict__ wsg)
{
    __shared__ __bf16 At[2][128][TP];
    __shared__ __bf16 Bt[2][128][TP];

    const int mb = blockIdx.x, nb = blockIdx.y;
    const int t = nb >> 1;                       // 0=q 1=k 2=v 3=g
    const float* X = (t == 0 || t == 3) ? qd : kvd;
    const int widx = (t == 0) ? 0 : (t == 1) ? 1 : (t == 2) ? 2 : 3;
    const __bf16* W = wBF + ((size_t)widx << 16) + (size_t)((nb & 1) * 128) * 256;

    const int tid = threadIdx.x;
    const int lane = tid & 63, w = tid >> 6;
    const int g = lane >> 4, kg = g * 8, c0 = lane & 15;
    const int mq = (w >> 1) * 64, nq = (w & 1) * 64;
    const int m0 = mb * 128;

    const int srow = tid >> 1, shalf = (tid & 1) * 32;   // staging: half-row per thread

    f32x4 acc[4][4] = {};

    // ---- staging helpers (registers) ----
    f32x4 av[8]; bf16x8 bv[4];
    auto load_stage = [&](int kit) {
        const float* ap = X + (size_t)(m0 + srow) * DIM + kit * 64 + shalf;
#pragma unroll
        for (int j = 0; j < 8; j++) av[j] = *(const f32x4*)(ap + j * 4);
        const __bf16* bp = W + (size_t)srow * 256 + kit * 64 + shalf;
#pragma unroll
        for (int j = 0; j < 4; j++) bv[j] = *(const bf16x8*)(bp + j * 8);
    };
    auto write_stage = [&](int buf) {
#pragma unroll
        for (int j = 0; j < 4; j++) {
            bf16x8 c;
            f32x4 lo = av[j * 2], hi = av[j * 2 + 1];
            c[0] = (__bf16)lo[0]; c[1] = (__bf16)lo[1]; c[2] = (__bf16)lo[2]; c[3] = (__bf16)lo[3];
            c[4] = (__bf16)hi[0]; c[5] = (__bf16)hi[1]; c[6] = (__bf16)hi[2]; c[7] = (__bf16)hi[3];
            *(bf16x8*)(&At[buf][srow][shalf + j * 8]) = c;
            *(bf16x8*)(&Bt[buf][srow][shalf + j * 8]) = bv[j];
        }
    };

    load_stage(0);
    write_stage(0);
    __syncthreads();

#pragma unroll
    for (int kit = 0; kit < 4; kit++) {
        if (kit < 3) load_stage(kit + 1);
        const int cur = kit & 1;
#pragma unroll
        for (int ks = 0; ks < 2; ks++) {
            bf16x8 af[4], bf_[4];
#pragma unroll
            for (int mi = 0; mi < 4; mi++)
                af[mi] = *(const bf16x8*)(&At[cur][mq + mi * 16 + c0][ks * 32 + kg]);
#pragma unroll
            for (int ni = 0; ni < 4; ni++)
                bf_[ni] = *(const bf16x8*)(&Bt[cur][nq + ni * 16 + c0][ks * 32 + kg]);
#pragma unroll
            for (int mi = 0; mi < 4; mi++)
#pragma unroll
                for (int ni = 0; ni < 4; ni++)
                    acc[mi][ni] = MFMA16(af[mi], bf_[ni], acc[mi][ni], 0, 0, 0);
        }
        if (kit < 3) write_stage(cur ^ 1);
        __syncthreads();
    }

    // ---- epilogue ----
#pragma unroll
    for (int ni = 0; ni < 4; ni++) {
        const int nloc = (nb & 1) * 128 + nq + ni * 16 + c0;   // 0..255 within type
        const int h = nloc >> 5, c = nloc & 31;
        const float bg_ = (t == 3) ? bg[nloc] : 0.0f;
#pragma unroll
        for (int mi = 0; mi < 4; mi++) {
            const int mbase = m0 + mq + mi * 16 + g * 4;
            const int b2 = mbase >> 8;
            if (t == 2) {
                // v transposed: wsvT[b2h][c][l], l contiguous over reg
                bf16x4 pk;
#pragma unroll
                for (int reg = 0; reg < 4; reg++) pk[reg] = (__bf16)acc[mi][ni][reg];
                *(bf16x4*)(&wsvT[((size_t)(b2 * NH + h) * CC + c) * LQK + (mbase & 255)]) = pk;
            } else {
#pragma unroll
                for (int reg = 0; reg < 4; reg++) {
                    const int l = (mbase + reg) & 255;
                    float v = acc[mi][ni][reg];
                    size_t idx = ((size_t)(b2 * NH + h) * LQK + l) * CC + c;
                    if (t == 0)      wsq[idx] = (__bf16)(v * 0.17677669529663689f);
                    else if (t == 1) wsk[idx] = (__bf16)v;
                    else             wsg[idx] = (__bf16)(1.0f / (1.0f + __expf(-(v + bg_))));
                }
            }
        }
    }
}

// ---------------- Kernel 2: attention core (S^T orientation) --------------
// grid 4096 = b2(128)*h(8)*qt(4); 256 thr (4 waves), wave = 16 q-rows.
__global__ __launch_bounds__(256) void k_attn(
    const __bf16* __restrict__ wsq, const __bf16* __restrict__ wsk,
    const __bf16* __restrict__ wsvT, const __bf16* __restrict__ wsg,
    const float* __restrict__ bias, const float* __restrict__ nbb,
    __bf16* __restrict__ wswa)
{
    __shared__ __bf16 P[4][16][264];

    const int bid = blockIdx.x;
    const int b2 = bid >> 5, h = (bid >> 2) & 7, qt = bid & 3;
    const int lane = threadIdx.x & 63, w = threadIdx.x >> 6;
    const int g = lane >> 4, kg = g * 8, c0 = lane & 15;
    const int qbase = qt * 64 + w * 16;

    const __bf16* qp = wsq + (size_t)(b2 * NH + h) * LQK * CC;
    const __bf16* kp = wsk + (size_t)(b2 * NH + h) * LQK * CC;
    const __bf16* vT = wsvT + (size_t)(b2 * NH + h) * CC * LQK;
    const __bf16* gp = wsg + (size_t)(b2 * NH + h) * LQK * CC;
    const float* bp = bias + (size_t)(b2 * NH + h) * LQK * LQK;
    const float* np = nbb + (size_t)h * LQK * LQK;

    const int q = qbase + c0;                 // this lane's q-row (D-col)

    // S^T = K @ Q^T : A-frag = K rows (k-index), B-frag = Q rows (q-index)
    // s[nt][reg]: k = nt*16 + 4g + reg, q = qbase + c0
    f32x4 s[16];
    bf16x8 qf = *(const bf16x8*)(qp + (size_t)q * CC + kg);
#pragma unroll
    for (int nt = 0; nt < 16; nt++) {
        bf16x8 kf = *(const bf16x8*)(kp + (size_t)(nt * 16 + c0) * CC + kg);
        f32x4 z = {};
        s[nt] = MFMA16(kf, qf, z, 0, 0, 0);
    }
    // + bias + nonbatched_bias : contiguous f32x4 per lane
#pragma unroll
    for (int nt = 0; nt < 16; nt++) {
        f32x4 b4 = *(const f32x4*)(bp + (size_t)q * LQK + nt * 16 + g * 4);
        f32x4 n4 = *(const f32x4*)(np + (size_t)q * LQK + nt * 16 + g * 4);
#pragma unroll
        for (int reg = 0; reg < 4; reg++) s[nt][reg] += b4[reg] + n4[reg];
    }
    // softmax over k (64 local values + 2 shuffles across g-groups)
    float mx = s[0][0];
#pragma unroll
    for (int nt = 0; nt < 16; nt++)
#pragma unroll
        for (int reg = 0; reg < 4; reg++) mx = fmaxf(mx, s[nt][reg]);
    mx = fmaxf(mx, __shfl_xor(mx, 16));
    mx = fmaxf(mx, __shfl_xor(mx, 32));
    float sm = 0.0f;
#pragma unroll
    for (int nt = 0; nt < 16; nt++)
#pragma unroll
        for (int reg = 0; reg < 4; reg++) {
            float e = __expf(s[nt][reg] - mx);
            s[nt][reg] = e;
            sm += e;
        }
    sm += __shfl_xor(sm, 16);
    sm += __shfl_xor(sm, 32);
    const float inv = 1.0f / sm;

    // P -> LDS: P[q=c0][k], b64 writes (4 consecutive k per reg-quad)
#pragma unroll
    for (int nt = 0; nt < 16; nt++) {
        bf16x4 pk;
#pragma unroll
        for (int reg = 0; reg < 4; reg++) pk[reg] = (__bf16)s[nt][reg];
        *(bf16x4*)(&P[w][c0][nt * 16 + g * 4]) = pk;
    }
    __syncthreads();

    // O = P @ V
    f32x4 o[2] = {};
#pragma unroll
    for (int kt = 0; kt < 8; kt++) {
        bf16x8 pa = *(const bf16x8*)(&P[w][c0][kt * 32 + kg]);
#pragma unroll
        for (int nt = 0; nt < 2; nt++) {
            bf16x8 vb = *(const bf16x8*)(vT + (size_t)(nt * 16 + c0) * LQK + kt * 32 + kg);
            o[nt] = MFMA16(pa, vb, o[nt], 0, 0, 0);
        }
    }
    // 1/sum (broadcast via shfl: lane needs inv of its own q... o-layout:
    // D col=c0 -> v-col c, row=4g+reg -> q-row within tile)
#pragma unroll
    for (int nt = 0; nt < 2; nt++) {
#pragma unroll
        for (int reg = 0; reg < 4; reg++) {
            int row = qbase + g * 4 + reg;
            int c = nt * 16 + c0;
            // fetch inv-sum of row: it lives in lane (row-qbase) of this wave
            float invr = __shfl(inv, (row - qbase) + (w << 6) - (w << 6), 64);
            invr = __shfl(inv, row - qbase, 64);
            float val = o[nt][reg] * invr;
            val *= (float)gp[(size_t)row * CC + c];
            wswa[((size_t)(b2 * LQK + row)) * (NH * CC) + h * CC + c] = (__bf16)val;
        }
    }
}

// ---------------- Kernel 3: output projection (tiled GEMM) ----------------
// M=32768, N=256, K=256. grid (256, 2), 256 thr. Same structure as k_proj.
__global__ __launch_bounds__(256, 2) void k_out(
    const __bf16* __restrict__ wa, const __bf16* __restrict__ wBF,
    const float* __restrict__ bo, float* __restrict__ out)
{
    __shared__ __bf16 At[2][128][TP];
    __shared__ __bf16 Bt[2][128][TP];

    const int mb = blockIdx.x, nb = blockIdx.y;
    const __bf16* W = wBF + ((size_t)4 << 16) + (size_t)(nb * 128) * 256;

    const int tid = threadIdx.x;
    const int lane = tid & 63, w = tid >> 6;
    const int g = lane >> 4, kg = g * 8, c0 = lane & 15;
    const int mq = (w >> 1) * 64, nq = (w & 1) * 64;
    const int m0 = mb * 128;
    const int srow = tid >> 1, shalf = (tid & 1) * 32;

    f32x4 acc[4][4] = {};
    bf16x8 av[4], bv[4];
    auto load_stage = [&](int kit) {
        const __bf16* ap = wa + (size_t)(m0 + srow) * 256 + kit * 64 + shalf;
        const __bf16* bp = W + (size_t)srow * 256 + kit * 64 + shalf;
#pragma unroll
        for (int j = 0; j < 4; j++) {
            av[j] = *(const bf16x8*)(ap + j * 8);
            bv[j] = *(const bf16x8*)(bp + j * 8);
        }
    };
    auto write_stage = [&](int buf) {
#pragma unroll
        for (int j = 0; j < 4; j++) {
            *(bf16x8*)(&At[buf][srow][shalf + j * 8]) = av[j];
            *(bf16x8*)(&Bt[buf][srow][shalf + j * 8]) = bv[j];
        }
    };

    load_stage(0);
    write_stage(0);
    __syncthreads();

#pragma unroll
    for (int kit = 0; kit < 4; kit++) {
        if (kit < 3) load_stage(kit + 1);
        const int cur = kit & 1;
#pragma unroll
        for (int ks = 0; ks < 2; ks++) {
            bf16x8 af[4], bf_[4];
#pragma unroll
            for (int mi = 0; mi < 4; mi++)
                af[mi] = *(const bf16x8*)(&At[cur][mq + mi * 16 + c0][ks * 32 + kg]);
#pragma unroll
            for (int ni = 0; ni < 4; ni++)
                bf_[ni] = *(const bf16x8*)(&Bt[cur][nq + ni * 16 + c0][ks * 32 + kg]);
#pragma unroll
            for (int mi = 0; mi < 4; mi++)
#pragma unroll
                for (int ni = 0; ni < 4; ni++)
                    acc[mi][ni] = MFMA16(af[mi], bf_[ni], acc[mi][ni], 0, 0, 0);
        }
        if (kit < 3) write_stage(cur ^ 1);
        __syncthreads();
    }

#pragma unroll
    for (int ni = 0; ni < 4; ni++) {
        const int n = nb * 128 + nq + ni * 16 + c0;
        const float bo_ = bo[n];
#pragma unroll
        for (int mi = 0; mi < 4; mi++) {
            const int mbase = m0 + mq + mi * 16 + g * 4;
#pragma unroll
            for (int reg = 0; reg < 4; reg++)
                out[(size_t)(mbase + reg) * 256 + n] = acc[mi][ni][reg] + bo_;
        }
    }
}

// ---------------- launcher ------------------------------------------------
extern "C" void kernel_launch(void* const* d_in, const int* in_sizes, int n_in,
                              void* d_out, int out_size, void* d_ws, size_t ws_size,
                              hipStream_t stream) {
    const float* qd  = (const float*)d_in[0];
    const float* kvd = (const float*)d_in[1];
    const float* bias = (const float*)d_in[2];
    const float* nbb = (const float*)d_in[3];
    const float* Wq = (const float*)d_in[4];
    const float* Wk = (const float*)d_in[5];
    const float* Wv = (const float*)d_in[6];
    const float* Wg = (const float*)d_in[7];
    const float* bg = (const float*)d_in[8];
    const float* Wo = (const float*)d_in[9];
    const float* bo = (const float*)d_in[10];
    float* out = (float*)d_out;

    const size_t NTOK = (size_t)NB2 * LQK * NH * CC;  // 8,388,608
    __bf16* ws = (__bf16*)d_ws;
    __bf16* wsq  = ws;
    __bf16* wsk  = wsq + NTOK;
    __bf16* wsvT = wsk + NTOK;
    __bf16* wsg  = wsvT + NTOK;
    __bf16* wswa = wsg + NTOK;
    __bf16* wBF  = wswa + NTOK;        // 5 * 65536 bf16 weights

    k_wcvt<<<dim3(320), 256, 0, stream>>>(Wq, Wk, Wv, Wg, Wo, wBF);
    k_proj<<<dim3(256, 8), 256, 0, stream>>>(qd, kvd, wBF, bg,
                                             wsq, wsk, wsvT, wsg);
    k_attn<<<dim3(4096), 256, 0, stream>>>(wsq, wsk, wsvT, wsg, bias, nbb, wswa);
    k_out<<<dim3(256, 2), 256, 0, stream>>>(wswa, wBF, bo, out);
}

// Round 5
// 234.490 us; speedup vs baseline: 1.9946x; 1.0815x over previous
//
#include <hip/hip_runtime.h>
#include <hip/hip_bf16.h>

// dims
#define NB2 128
#define LQK 256
#define DIM 256
#define NH 8
#define CC 32

typedef __bf16 bf16x8 __attribute__((ext_vector_type(8)));
typedef __bf16 bf16x4 __attribute__((ext_vector_type(4)));
typedef float f32x4 __attribute__((ext_vector_type(4)));

#define MFMA16 __builtin_amdgcn_mfma_f32_16x16x32_bf16

// LDS tile row stride (bf16): 64 k + 8 pad
#define TP 72

#define NTOK ((size_t)NB2 * LQK * NH * CC)   // 8,388,608

// ---------------- Kernel 0a: weights fp32 -> bf16 -------------------------
__global__ __launch_bounds__(256) void k_wcvt(
    const float* __restrict__ Wq, const float* __restrict__ Wk,
    const float* __restrict__ Wv, const float* __restrict__ Wg,
    const float* __restrict__ Wo, __bf16* __restrict__ dst)
{
    int i = (blockIdx.x * 256 + threadIdx.x) * 4;
    int mat = i >> 16;
    int off = i & 65535;
    const float* src = (mat == 0) ? Wq : (mat == 1) ? Wk : (mat == 2) ? Wv
                      : (mat == 3) ? Wg : Wo;
    f32x4 v = *(const f32x4*)(src + off);
    __bf16* d = dst + ((size_t)mat << 16) + off;
    d[0] = (__bf16)v[0]; d[1] = (__bf16)v[1]; d[2] = (__bf16)v[2]; d[3] = (__bf16)v[3];
}

// ---------------- Kernel 0b: activations fp32 -> bf16 ---------------------
// qd then kvd, 8 elems/thread. grid = 2*NTOK/(256*8) = 8192 blocks.
__global__ __launch_bounds__(256) void k_acvt(
    const float* __restrict__ qd, const float* __restrict__ kvd,
    __bf16* __restrict__ qbf, __bf16* __restrict__ kvbf)
{
    size_t i = ((size_t)blockIdx.x * 256 + threadIdx.x) * 8;
    const float* src;
    __bf16* dst;
    if (i < NTOK) { src = qd + i; dst = qbf + i; }
    else          { src = kvd + (i - NTOK); dst = kvbf + (i - NTOK); }
    f32x4 a = *(const f32x4*)src;
    f32x4 b = *(const f32x4*)(src + 4);
    bf16x8 r;
    r[0] = (__bf16)a[0]; r[1] = (__bf16)a[1]; r[2] = (__bf16)a[2]; r[3] = (__bf16)a[3];
    r[4] = (__bf16)b[0]; r[5] = (__bf16)b[1]; r[6] = (__bf16)b[2]; r[7] = (__bf16)b[3];
    *(bf16x8*)dst = r;
}

// ---------------- Kernel 1: QKVG projection (tiled GEMM, bf16 A) ----------
// M=32768, N=1024=[q|k|v|g], K=256.  grid (256 mb, 8 nb), 256 thr (4 waves).
__global__ __launch_bounds__(256, 2) void k_proj(
    const __bf16* __restrict__ qbf, const __bf16* __restrict__ kvbf,
    const __bf16* __restrict__ wBF, const float* __restrict__ bg,
    __bf16* __restrict__ wsq, __bf16* __restrict__ wsk,
    __bf16* __restrict__ wsvT, __bf16* __restrict__ wsgT)
{
    __shared__ __bf16 At[2][128][TP];
    __shared__ __bf16 Bt[2][128][TP];

    const int mb = blockIdx.x, nb = blockIdx.y;
    const int t = nb >> 1;                       // 0=q 1=k 2=v 3=g
    const __bf16* X = (t == 0 || t == 3) ? qbf : kvbf;
    const __bf16* W = wBF + ((size_t)t << 16) + (size_t)((nb & 1) * 128) * 256;

    const int tid = threadIdx.x;
    const int lane = tid & 63, w = tid >> 6;
    const int g = lane >> 4, kg = g * 8, c0 = lane & 15;
    const int mq = (w >> 1) * 64, nq = (w & 1) * 64;
    const int m0 = mb * 128;
    const int srow = tid >> 1, shalf = (tid & 1) * 32;

    f32x4 acc[4][4] = {};
    bf16x8 av[4], bv[4];
    auto load_stage = [&](int kit) {
        const __bf16* ap = X + (size_t)(m0 + srow) * DIM + kit * 64 + shalf;
        const __bf16* bp = W + (size_t)srow * 256 + kit * 64 + shalf;
#pragma unroll
        for (int j = 0; j < 4; j++) {
            av[j] = *(const bf16x8*)(ap + j * 8);
            bv[j] = *(const bf16x8*)(bp + j * 8);
        }
    };
    auto write_stage = [&](int buf) {
#pragma unroll
        for (int j = 0; j < 4; j++) {
            *(bf16x8*)(&At[buf][srow][shalf + j * 8]) = av[j];
            *(bf16x8*)(&Bt[buf][srow][shalf + j * 8]) = bv[j];
        }
    };

    load_stage(0);
    write_stage(0);
    __syncthreads();

#pragma unroll
    for (int kit = 0; kit < 4; kit++) {
        if (kit < 3) load_stage(kit + 1);
        const int cur = kit & 1;
#pragma unroll
        for (int ks = 0; ks < 2; ks++) {
            bf16x8 af[4], bf_[4];
#pragma unroll
            for (int mi = 0; mi < 4; mi++)
                af[mi] = *(const bf16x8*)(&At[cur][mq + mi * 16 + c0][ks * 32 + kg]);
#pragma unroll
            for (int ni = 0; ni < 4; ni++)
                bf_[ni] = *(const bf16x8*)(&Bt[cur][nq + ni * 16 + c0][ks * 32 + kg]);
#pragma unroll
            for (int mi = 0; mi < 4; mi++)
#pragma unroll
                for (int ni = 0; ni < 4; ni++)
                    acc[mi][ni] = MFMA16(af[mi], bf_[ni], acc[mi][ni], 0, 0, 0);
        }
        if (kit < 3) write_stage(cur ^ 1);
        __syncthreads();
    }

    // ---- epilogue ----
#pragma unroll
    for (int ni = 0; ni < 4; ni++) {
        const int nloc = (nb & 1) * 128 + nq + ni * 16 + c0;   // 0..255 within type
        const int h = nloc >> 5, c = nloc & 31;
        const float bg_ = (t == 3) ? bg[nloc] : 0.0f;
#pragma unroll
        for (int mi = 0; mi < 4; mi++) {
            const int mbase = m0 + mq + mi * 16 + g * 4;
            const int b2 = mbase >> 8;
            if (t == 2) {
                bf16x4 pk;
#pragma unroll
                for (int reg = 0; reg < 4; reg++) pk[reg] = (__bf16)acc[mi][ni][reg];
                *(bf16x4*)(&wsvT[((size_t)(b2 * NH + h) * CC + c) * LQK + (mbase & 255)]) = pk;
            } else if (t == 3) {
                bf16x4 pk;
#pragma unroll
                for (int reg = 0; reg < 4; reg++)
                    pk[reg] = (__bf16)(1.0f / (1.0f + __expf(-(acc[mi][ni][reg] + bg_))));
                *(bf16x4*)(&wsgT[((size_t)(b2 * NH + h) * CC + c) * LQK + (mbase & 255)]) = pk;
            } else {
#pragma unroll
                for (int reg = 0; reg < 4; reg++) {
                    const int l = (mbase + reg) & 255;
                    float v = acc[mi][ni][reg];
                    size_t idx = ((size_t)(b2 * NH + h) * LQK + l) * CC + c;
                    if (t == 0) wsq[idx] = (__bf16)(v * 0.17677669529663689f);
                    else        wsk[idx] = (__bf16)v;
                }
            }
        }
    }
}

// ---------------- Kernel 2: attention core (S^T, bias-prefetch) -----------
// grid 4096 = b2(128)*h(8)*qt(4); 256 thr (4 waves), wave = 16 q-rows.
__global__ __launch_bounds__(256) void k_attn(
    const __bf16* __restrict__ wsq, const __bf16* __restrict__ wsk,
    const __bf16* __restrict__ wsvT, const __bf16* __restrict__ wsgT,
    const float* __restrict__ bias, const float* __restrict__ nbb,
    __bf16* __restrict__ wswa)
{
    __shared__ __bf16 P[4][16][264];

    const int bid = blockIdx.x;
    const int b2 = bid >> 5, h = (bid >> 2) & 7, qt = bid & 3;
    const int lane = threadIdx.x & 63, w = threadIdx.x >> 6;
    const int g = lane >> 4, kg = g * 8, c0 = lane & 15;
    const int qbase = qt * 64 + w * 16;
    const int q = qbase + c0;                 // this lane's q-row

    const __bf16* qp = wsq + (size_t)(b2 * NH + h) * LQK * CC;
    const __bf16* kp = wsk + (size_t)(b2 * NH + h) * LQK * CC;
    const __bf16* vT = wsvT + (size_t)(b2 * NH + h) * CC * LQK;
    const __bf16* gT = wsgT + (size_t)(b2 * NH + h) * CC * LQK;
    const float* bp = bias + ((size_t)(b2 * NH + h) * LQK + q) * LQK;
    const float* np = nbb + ((size_t)h * LQK + q) * LQK;

    // ---- phase 0: issue ALL bias/nbb loads first (independent of q/k) ----
    f32x4 bsum[16];
#pragma unroll
    for (int nt = 0; nt < 16; nt++) {
        f32x4 b4 = *(const f32x4*)(bp + nt * 16 + g * 4);
        f32x4 n4 = *(const f32x4*)(np + nt * 16 + g * 4);
#pragma unroll
        for (int reg = 0; reg < 4; reg++) bsum[nt][reg] = b4[reg] + n4[reg];
    }

    // ---- S^T = K @ Q^T : s[nt][reg]: k = nt*16+4g+reg, q = qbase+c0 ----
    f32x4 s[16];
    bf16x8 qf = *(const bf16x8*)(qp + (size_t)q * CC + kg);
#pragma unroll
    for (int nt = 0; nt < 16; nt++) {
        bf16x8 kf = *(const bf16x8*)(kp + (size_t)(nt * 16 + c0) * CC + kg);
        f32x4 z = {};
        s[nt] = MFMA16(kf, qf, z, 0, 0, 0);
    }
#pragma unroll
    for (int nt = 0; nt < 16; nt++)
#pragma unroll
        for (int reg = 0; reg < 4; reg++) s[nt][reg] += bsum[nt][reg];

    // ---- softmax over k (64 local + 2 shuffles) ----
    float mx = s[0][0];
#pragma unroll
    for (int nt = 0; nt < 16; nt++)
#pragma unroll
        for (int reg = 0; reg < 4; reg++) mx = fmaxf(mx, s[nt][reg]);
    mx = fmaxf(mx, __shfl_xor(mx, 16));
    mx = fmaxf(mx, __shfl_xor(mx, 32));
    float sm = 0.0f;
#pragma unroll
    for (int nt = 0; nt < 16; nt++)
#pragma unroll
        for (int reg = 0; reg < 4; reg++) {
            float e = __expf(s[nt][reg] - mx);
            s[nt][reg] = e;
            sm += e;
        }
    sm += __shfl_xor(sm, 16);
    sm += __shfl_xor(sm, 32);
    const float inv = 1.0f / sm;

    // ---- P -> LDS: P[q=c0][k], b64 writes ----
#pragma unroll
    for (int nt = 0; nt < 16; nt++) {
        bf16x4 pk;
#pragma unroll
        for (int reg = 0; reg < 4; reg++) pk[reg] = (__bf16)s[nt][reg];
        *(bf16x4*)(&P[w][c0][nt * 16 + g * 4]) = pk;
    }
    __syncthreads();

    // ---- O = P @ V ----
    f32x4 o[2] = {};
#pragma unroll
    for (int kt = 0; kt < 8; kt++) {
        bf16x8 pa = *(const bf16x8*)(&P[w][c0][kt * 32 + kg]);
#pragma unroll
        for (int nt = 0; nt < 2; nt++) {
            bf16x8 vb = *(const bf16x8*)(vT + (size_t)(nt * 16 + c0) * LQK + kt * 32 + kg);
            o[nt] = MFMA16(pa, vb, o[nt], 0, 0, 0);
        }
    }
    // ---- 1/sum, gate (transposed, bf16x4), store ----
#pragma unroll
    for (int nt = 0; nt < 2; nt++) {
        const int c = nt * 16 + c0;
        bf16x4 g4 = *(const bf16x4*)(gT + (size_t)c * LQK + qbase + g * 4);
#pragma unroll
        for (int reg = 0; reg < 4; reg++) {
            const int row = qbase + g * 4 + reg;
            const float invr = __shfl(inv, g * 4 + reg, 64);
            const float val = o[nt][reg] * invr * (float)g4[reg];
            wswa[((size_t)(b2 * LQK + row)) * (NH * CC) + h * CC + c] = (__bf16)val;
        }
    }
}

// ---------------- Kernel 3: output projection (tiled GEMM) ----------------
__global__ __launch_bounds__(256, 2) void k_out(
    const __bf16* __restrict__ wa, const __bf16* __restrict__ wBF,
    const float* __restrict__ bo, float* __restrict__ out)
{
    __shared__ __bf16 At[2][128][TP];
    __shared__ __bf16 Bt[2][128][TP];

    const int mb = blockIdx.x, nb = blockIdx.y;
    const __bf16* W = wBF + ((size_t)4 << 16) + (size_t)(nb * 128) * 256;

    const int tid = threadIdx.x;
    const int lane = tid & 63, w = tid >> 6;
    const int g = lane >> 4, kg = g * 8, c0 = lane & 15;
    const int mq = (w >> 1) * 64, nq = (w & 1) * 64;
    const int m0 = mb * 128;
    const int srow = tid >> 1, shalf = (tid & 1) * 32;

    f32x4 acc[4][4] = {};
    bf16x8 av[4], bv[4];
    auto load_stage = [&](int kit) {
        const __bf16* ap = wa + (size_t)(m0 + srow) * 256 + kit * 64 + shalf;
        const __bf16* bp = W + (size_t)srow * 256 + kit * 64 + shalf;
#pragma unroll
        for (int j = 0; j < 4; j++) {
            av[j] = *(const bf16x8*)(ap + j * 8);
            bv[j] = *(const bf16x8*)(bp + j * 8);
        }
    };
    auto write_stage = [&](int buf) {
#pragma unroll
        for (int j = 0; j < 4; j++) {
            *(bf16x8*)(&At[buf][srow][shalf + j * 8]) = av[j];
            *(bf16x8*)(&Bt[buf][srow][shalf + j * 8]) = bv[j];
        }
    };

    load_stage(0);
    write_stage(0);
    __syncthreads();

#pragma unroll
    for (int kit = 0; kit < 4; kit++) {
        if (kit < 3) load_stage(kit + 1);
        const int cur = kit & 1;
#pragma unroll
        for (int ks = 0; ks < 2; ks++) {
            bf16x8 af[4], bf_[4];
#pragma unroll
            for (int mi = 0; mi < 4; mi++)
                af[mi] = *(const bf16x8*)(&At[cur][mq + mi * 16 + c0][ks * 32 + kg]);
#pragma unroll
            for (int ni = 0; ni < 4; ni++)
                bf_[ni] = *(const bf16x8*)(&Bt[cur][nq + ni * 16 + c0][ks * 32 + kg]);
#pragma unroll
            for (int mi = 0; mi < 4; mi++)
#pragma unroll
                for (int ni = 0; ni < 4; ni++)
                    acc[mi][ni] = MFMA16(af[mi], bf_[ni], acc[mi][ni], 0, 0, 0);
        }
        if (kit < 3) write_stage(cur ^ 1);
        __syncthreads();
    }

#pragma unroll
    for (int ni = 0; ni < 4; ni++) {
        const int n = nb * 128 + nq + ni * 16 + c0;
        const float bo_ = bo[n];
#pragma unroll
        for (int mi = 0; mi < 4; mi++) {
            const int mbase = m0 + mq + mi * 16 + g * 4;
#pragma unroll
            for (int reg = 0; reg < 4; reg++)
                out[(size_t)(mbase + reg) * 256 + n] = acc[mi][ni][reg] + bo_;
        }
    }
}

// ---------------- launcher ------------------------------------------------
extern "C" void kernel_launch(void* const* d_in, const int* in_sizes, int n_in,
                              void* d_out, int out_size, void* d_ws, size_t ws_size,
                              hipStream_t stream) {
    const float* qd  = (const float*)d_in[0];
    const float* kvd = (const float*)d_in[1];
    const float* bias = (const float*)d_in[2];
    const float* nbb = (const float*)d_in[3];
    const float* Wq = (const float*)d_in[4];
    const float* Wk = (const float*)d_in[5];
    const float* Wv = (const float*)d_in[6];
    const float* Wg = (const float*)d_in[7];
    const float* bg = (const float*)d_in[8];
    const float* Wo = (const float*)d_in[9];
    const float* bo = (const float*)d_in[10];
    float* out = (float*)d_out;

    __bf16* ws = (__bf16*)d_ws;
    __bf16* wsq  = ws;
    __bf16* wsk  = wsq + NTOK;
    __bf16* wsvT = wsk + NTOK;
    __bf16* wsgT = wsvT + NTOK;
    __bf16* wBF  = wsgT + NTOK;            // 5 * 65536 bf16 weights
    __bf16* qbf  = wBF + 5 * 65536;        // activations bf16 (dead after k_proj)
    __bf16* kvbf = qbf + NTOK;
    __bf16* wswa = qbf;                    // alias: written by k_attn after k_proj

    k_wcvt<<<dim3(320), 256, 0, stream>>>(Wq, Wk, Wv, Wg, Wo, wBF);
    k_acvt<<<dim3(8192), 256, 0, stream>>>(qd, kvd, qbf, kvbf);
    k_proj<<<dim3(256, 8), 256, 0, stream>>>(qbf, kvbf, wBF, bg,
                                             wsq, wsk, wsvT, wsgT);
    k_attn<<<dim3(4096), 256, 0, stream>>>(wsq, wsk, wsvT, wsgT, bias, nbb, wswa);
    k_out<<<dim3(256, 2), 256, 0, stream>>>(wswa, wBF, bo, out);
}

// Round 6
// 196.052 us; speedup vs baseline: 2.3857x; 1.1961x over previous
//
#include <hip/hip_runtime.h>
#include <hip/hip_bf16.h>

// dims
#define NB2 128
#define LQK 256
#define DIM 256
#define NH 8
#define CC 32

typedef __bf16 bf16x8 __attribute__((ext_vector_type(8)));
typedef __bf16 bf16x4 __attribute__((ext_vector_type(4)));
typedef float f32x4 __attribute__((ext_vector_type(4)));

#define MFMA16 __builtin_amdgcn_mfma_f32_16x16x32_bf16

// LDS tile row stride (bf16): 64 k + 8 pad
#define TP 72

#define NTOK ((size_t)NB2 * LQK * NH * CC)   // 8,388,608

// ---------------- Kernel 0a: weights fp32 -> bf16 -------------------------
__global__ __launch_bounds__(256) void k_wcvt(
    const float* __restrict__ Wq, const float* __restrict__ Wk,
    const float* __restrict__ Wv, const float* __restrict__ Wg,
    const float* __restrict__ Wo, __bf16* __restrict__ dst)
{
    int i = (blockIdx.x * 256 + threadIdx.x) * 4;
    int mat = i >> 16;
    int off = i & 65535;
    const float* src = (mat == 0) ? Wq : (mat == 1) ? Wk : (mat == 2) ? Wv
                      : (mat == 3) ? Wg : Wo;
    f32x4 v = *(const f32x4*)(src + off);
    __bf16* d = dst + ((size_t)mat << 16) + off;
    d[0] = (__bf16)v[0]; d[1] = (__bf16)v[1]; d[2] = (__bf16)v[2]; d[3] = (__bf16)v[3];
}

// ---------------- Kernel 0b: activations fp32 -> bf16 ---------------------
__global__ __launch_bounds__(256) void k_acvt(
    const float* __restrict__ qd, const float* __restrict__ kvd,
    __bf16* __restrict__ qbf, __bf16* __restrict__ kvbf)
{
    size_t i = ((size_t)blockIdx.x * 256 + threadIdx.x) * 8;
    const float* src;
    __bf16* dst;
    if (i < NTOK) { src = qd + i; dst = qbf + i; }
    else          { src = kvd + (i - NTOK); dst = kvbf + (i - NTOK); }
    f32x4 a = *(const f32x4*)src;
    f32x4 b = *(const f32x4*)(src + 4);
    bf16x8 r;
    r[0] = (__bf16)a[0]; r[1] = (__bf16)a[1]; r[2] = (__bf16)a[2]; r[3] = (__bf16)a[3];
    r[4] = (__bf16)b[0]; r[5] = (__bf16)b[1]; r[6] = (__bf16)b[2]; r[7] = (__bf16)b[3];
    *(bf16x8*)dst = r;
}

// ---------------- Kernel 1: QKVG projection (tiled GEMM, bf16 A) ----------
__global__ __launch_bounds__(256, 2) void k_proj(
    const __bf16* __restrict__ qbf, const __bf16* __restrict__ kvbf,
    const __bf16* __restrict__ wBF, const float* __restrict__ bg,
    __bf16* __restrict__ wsq, __bf16* __restrict__ wsk,
    __bf16* __restrict__ wsvT, __bf16* __restrict__ wsgT)
{
    __shared__ __bf16 At[2][128][TP];
    __shared__ __bf16 Bt[2][128][TP];

    const int mb = blockIdx.x, nb = blockIdx.y;
    const int t = nb >> 1;                       // 0=q 1=k 2=v 3=g
    const __bf16* X = (t == 0 || t == 3) ? qbf : kvbf;
    const __bf16* W = wBF + ((size_t)t << 16) + (size_t)((nb & 1) * 128) * 256;

    const int tid = threadIdx.x;
    const int lane = tid & 63, w = tid >> 6;
    const int g = lane >> 4, kg = g * 8, c0 = lane & 15;
    const int mq = (w >> 1) * 64, nq = (w & 1) * 64;
    const int m0 = mb * 128;
    const int srow = tid >> 1, shalf = (tid & 1) * 32;

    f32x4 acc[4][4] = {};
    bf16x8 av[4], bv[4];
    auto load_stage = [&](int kit) {
        const __bf16* ap = X + (size_t)(m0 + srow) * DIM + kit * 64 + shalf;
        const __bf16* bp = W + (size_t)srow * 256 + kit * 64 + shalf;
#pragma unroll
        for (int j = 0; j < 4; j++) {
            av[j] = *(const bf16x8*)(ap + j * 8);
            bv[j] = *(const bf16x8*)(bp + j * 8);
        }
    };
    auto write_stage = [&](int buf) {
#pragma unroll
        for (int j = 0; j < 4; j++) {
            *(bf16x8*)(&At[buf][srow][shalf + j * 8]) = av[j];
            *(bf16x8*)(&Bt[buf][srow][shalf + j * 8]) = bv[j];
        }
    };

    load_stage(0);
    write_stage(0);
    __syncthreads();

#pragma unroll
    for (int kit = 0; kit < 4; kit++) {
        if (kit < 3) load_stage(kit + 1);
        const int cur = kit & 1;
#pragma unroll
        for (int ks = 0; ks < 2; ks++) {
            bf16x8 af[4], bf_[4];
#pragma unroll
            for (int mi = 0; mi < 4; mi++)
                af[mi] = *(const bf16x8*)(&At[cur][mq + mi * 16 + c0][ks * 32 + kg]);
#pragma unroll
            for (int ni = 0; ni < 4; ni++)
                bf_[ni] = *(const bf16x8*)(&Bt[cur][nq + ni * 16 + c0][ks * 32 + kg]);
#pragma unroll
            for (int mi = 0; mi < 4; mi++)
#pragma unroll
                for (int ni = 0; ni < 4; ni++)
                    acc[mi][ni] = MFMA16(af[mi], bf_[ni], acc[mi][ni], 0, 0, 0);
        }
        if (kit < 3) write_stage(cur ^ 1);
        __syncthreads();
    }

    // ---- epilogue ----
#pragma unroll
    for (int ni = 0; ni < 4; ni++) {
        const int nloc = (nb & 1) * 128 + nq + ni * 16 + c0;
        const int h = nloc >> 5, c = nloc & 31;
        const float bg_ = (t == 3) ? bg[nloc] : 0.0f;
#pragma unroll
        for (int mi = 0; mi < 4; mi++) {
            const int mbase = m0 + mq + mi * 16 + g * 4;
            const int b2 = mbase >> 8;
            if (t == 2) {
                bf16x4 pk;
#pragma unroll
                for (int reg = 0; reg < 4; reg++) pk[reg] = (__bf16)acc[mi][ni][reg];
                *(bf16x4*)(&wsvT[((size_t)(b2 * NH + h) * CC + c) * LQK + (mbase & 255)]) = pk;
            } else if (t == 3) {
                bf16x4 pk;
#pragma unroll
                for (int reg = 0; reg < 4; reg++)
                    pk[reg] = (__bf16)(1.0f / (1.0f + __expf(-(acc[mi][ni][reg] + bg_))));
                *(bf16x4*)(&wsgT[((size_t)(b2 * NH + h) * CC + c) * LQK + (mbase & 255)]) = pk;
            } else {
#pragma unroll
                for (int reg = 0; reg < 4; reg++) {
                    const int l = (mbase + reg) & 255;
                    float v = acc[mi][ni][reg];
                    size_t idx = ((size_t)(b2 * NH + h) * LQK + l) * CC + c;
                    if (t == 0) wsq[idx] = (__bf16)(v * 0.17677669529663689f);
                    else        wsk[idx] = (__bf16)v;
                }
            }
        }
    }
}

// ---------------- Kernel 2: attention core (no barrier, bias->MFMA C) -----
// grid 4096 = b2(128)*h(8)*qt(4); 256 thr (4 waves), wave-private P.
__global__ __launch_bounds__(256, 4) void k_attn(
    const __bf16* __restrict__ wsq, const __bf16* __restrict__ wsk,
    const __bf16* __restrict__ wsvT, const __bf16* __restrict__ wsgT,
    const float* __restrict__ bias, const float* __restrict__ nbb,
    __bf16* __restrict__ wswa)
{
    __shared__ __bf16 P[4][16][264];

    const int bid = blockIdx.x;
    const int b2 = bid >> 5, h = (bid >> 2) & 7, qt = bid & 3;
    const int lane = threadIdx.x & 63, w = threadIdx.x >> 6;
    const int g = lane >> 4, kg = g * 8, c0 = lane & 15;
    const int qbase = qt * 64 + w * 16;
    const int q = qbase + c0;                 // this lane's q-row

    const __bf16* qp = wsq + (size_t)(b2 * NH + h) * LQK * CC;
    const __bf16* kp = wsk + (size_t)(b2 * NH + h) * LQK * CC;
    const __bf16* vT = wsvT + (size_t)(b2 * NH + h) * CC * LQK;
    const __bf16* gT = wsgT + (size_t)(b2 * NH + h) * CC * LQK;
    const float* bp = bias + ((size_t)(b2 * NH + h) * LQK + q) * LQK;
    const float* np = nbb + ((size_t)h * LQK + q) * LQK;

    // ---- phase 0: bias+nbb loads -> s (becomes the MFMA C operand) ----
    f32x4 s[16];
#pragma unroll
    for (int nt = 0; nt < 16; nt++) {
        f32x4 b4 = *(const f32x4*)(bp + nt * 16 + g * 4);
        f32x4 n4 = *(const f32x4*)(np + nt * 16 + g * 4);
#pragma unroll
        for (int reg = 0; reg < 4; reg++) s[nt][reg] = b4[reg] + n4[reg];
    }

    // ---- S^T = K @ Q^T + bias : s[nt][reg]: k = nt*16+4g+reg, q col ----
    bf16x8 qf = *(const bf16x8*)(qp + (size_t)q * CC + kg);
#pragma unroll
    for (int nt = 0; nt < 16; nt++) {
        bf16x8 kf = *(const bf16x8*)(kp + (size_t)(nt * 16 + c0) * CC + kg);
        s[nt] = MFMA16(kf, qf, s[nt], 0, 0, 0);
    }

    // ---- softmax over k (64 local + 2 shuffles) ----
    float mx = s[0][0];
#pragma unroll
    for (int nt = 0; nt < 16; nt++)
#pragma unroll
        for (int reg = 0; reg < 4; reg++) mx = fmaxf(mx, s[nt][reg]);
    mx = fmaxf(mx, __shfl_xor(mx, 16));
    mx = fmaxf(mx, __shfl_xor(mx, 32));
    float sm = 0.0f;
#pragma unroll
    for (int nt = 0; nt < 16; nt++)
#pragma unroll
        for (int reg = 0; reg < 4; reg++) {
            float e = __expf(s[nt][reg] - mx);
            s[nt][reg] = e;
            sm += e;
        }
    sm += __shfl_xor(sm, 16);
    sm += __shfl_xor(sm, 32);
    const float inv = 1.0f / sm;

    // ---- P -> LDS (wave-private strip; NO barrier needed) ----
#pragma unroll
    for (int nt = 0; nt < 16; nt++) {
        bf16x4 pk;
#pragma unroll
        for (int reg = 0; reg < 4; reg++) pk[reg] = (__bf16)s[nt][reg];
        *(bf16x4*)(&P[w][c0][nt * 16 + g * 4]) = pk;
    }

    // ---- O = P @ V ----
    f32x4 o[2] = {};
#pragma unroll
    for (int kt = 0; kt < 8; kt++) {
        bf16x8 pa = *(const bf16x8*)(&P[w][c0][kt * 32 + kg]);
#pragma unroll
        for (int nt = 0; nt < 2; nt++) {
            bf16x8 vb = *(const bf16x8*)(vT + (size_t)(nt * 16 + c0) * LQK + kt * 32 + kg);
            o[nt] = MFMA16(pa, vb, o[nt], 0, 0, 0);
        }
    }
    // ---- 1/sum, gate (transposed, bf16x4), store ----
#pragma unroll
    for (int nt = 0; nt < 2; nt++) {
        const int c = nt * 16 + c0;
        bf16x4 g4 = *(const bf16x4*)(gT + (size_t)c * LQK + qbase + g * 4);
#pragma unroll
        for (int reg = 0; reg < 4; reg++) {
            const int row = qbase + g * 4 + reg;
            const float invr = __shfl(inv, g * 4 + reg, 64);
            const float val = o[nt][reg] * invr * (float)g4[reg];
            wswa[((size_t)(b2 * LQK + row)) * (NH * CC) + h * CC + c] = (__bf16)val;
        }
    }
}

// ---------------- Kernel 3: output projection (tiled GEMM) ----------------
__global__ __launch_bounds__(256, 2) void k_out(
    const __bf16* __restrict__ wa, const __bf16* __restrict__ wBF,
    const float* __restrict__ bo, float* __restrict__ out)
{
    __shared__ __bf16 At[2][128][TP];
    __shared__ __bf16 Bt[2][128][TP];

    const int mb = blockIdx.x, nb = blockIdx.y;
    const __bf16* W = wBF + ((size_t)4 << 16) + (size_t)(nb * 128) * 256;

    const int tid = threadIdx.x;
    const int lane = tid & 63, w = tid >> 6;
    const int g = lane >> 4, kg = g * 8, c0 = lane & 15;
    const int mq = (w >> 1) * 64, nq = (w & 1) * 64;
    const int m0 = mb * 128;
    const int srow = tid >> 1, shalf = (tid & 1) * 32;

    f32x4 acc[4][4] = {};
    bf16x8 av[4], bv[4];
    auto load_stage = [&](int kit) {
        const __bf16* ap = wa + (size_t)(m0 + srow) * 256 + kit * 64 + shalf;
        const __bf16* bp = W + (size_t)srow * 256 + kit * 64 + shalf;
#pragma unroll
        for (int j = 0; j < 4; j++) {
            av[j] = *(const bf16x8*)(ap + j * 8);
            bv[j] = *(const bf16x8*)(bp + j * 8);
        }
    };
    auto write_stage = [&](int buf) {
#pragma unroll
        for (int j = 0; j < 4; j++) {
            *(bf16x8*)(&At[buf][srow][shalf + j * 8]) = av[j];
            *(bf16x8*)(&Bt[buf][srow][shalf + j * 8]) = bv[j];
        }
    };

    load_stage(0);
    write_stage(0);
    __syncthreads();

#pragma unroll
    for (int kit = 0; kit < 4; kit++) {
        if (kit < 3) load_stage(kit + 1);
        const int cur = kit & 1;
#pragma unroll
        for (int ks = 0; ks < 2; ks++) {
            bf16x8 af[4], bf_[4];
#pragma unroll
            for (int mi = 0; mi < 4; mi++)
                af[mi] = *(const bf16x8*)(&At[cur][mq + mi * 16 + c0][ks * 32 + kg]);
#pragma unroll
            for (int ni = 0; ni < 4; ni++)
                bf_[ni] = *(const bf16x8*)(&Bt[cur][nq + ni * 16 + c0][ks * 32 + kg]);
#pragma unroll
            for (int mi = 0; mi < 4; mi++)
#pragma unroll
                for (int ni = 0; ni < 4; ni++)
                    acc[mi][ni] = MFMA16(af[mi], bf_[ni], acc[mi][ni], 0, 0, 0);
        }
        if (kit < 3) write_stage(cur ^ 1);
        __syncthreads();
    }

#pragma unroll
    for (int ni = 0; ni < 4; ni++) {
        const int n = nb * 128 + nq + ni * 16 + c0;
        const float bo_ = bo[n];
#pragma unroll
        for (int mi = 0; mi < 4; mi++) {
            const int mbase = m0 + mq + mi * 16 + g * 4;
#pragma unroll
            for (int reg = 0; reg < 4; reg++)
                out[(size_t)(mbase + reg) * 256 + n] = acc[mi][ni][reg] + bo_;
        }
    }
}

// ---------------- launcher ------------------------------------------------
extern "C" void kernel_launch(void* const* d_in, const int* in_sizes, int n_in,
                              void* d_out, int out_size, void* d_ws, size_t ws_size,
                              hipStream_t stream) {
    const float* qd  = (const float*)d_in[0];
    const float* kvd = (const float*)d_in[1];
    const float* bias = (const float*)d_in[2];
    const float* nbb = (const float*)d_in[3];
    const float* Wq = (const float*)d_in[4];
    const float* Wk = (const float*)d_in[5];
    const float* Wv = (const float*)d_in[6];
    const float* Wg = (const float*)d_in[7];
    const float* bg = (const float*)d_in[8];
    const float* Wo = (const float*)d_in[9];
    const float* bo = (const float*)d_in[10];
    float* out = (float*)d_out;

    __bf16* ws = (__bf16*)d_ws;
    __bf16* wsq  = ws;
    __bf16* wsk  = wsq + NTOK;
    __bf16* wsvT = wsk + NTOK;
    __bf16* wsgT = wsvT + NTOK;
    __bf16* wBF  = wsgT + NTOK;            // 5 * 65536 bf16 weights
    __bf16* qbf  = wBF + 5 * 65536;        // activations bf16 (dead after k_proj)
    __bf16* kvbf = qbf + NTOK;
    __bf16* wswa = qbf;                    // alias: written by k_attn after k_proj

    k_wcvt<<<dim3(320), 256, 0, stream>>>(Wq, Wk, Wv, Wg, Wo, wBF);
    k_acvt<<<dim3(8192), 256, 0, stream>>>(qd, kvd, qbf, kvbf);
    k_proj<<<dim3(256, 8), 256, 0, stream>>>(qbf, kvbf, wBF, bg,
                                             wsq, wsk, wsvT, wsgT);
    k_attn<<<dim3(4096), 256, 0, stream>>>(wsq, wsk, wsvT, wsgT, bias, nbb, wswa);
    k_out<<<dim3(256, 2), 256, 0, stream>>>(wswa, wBF, bo, out);
}